// Round 5
// baseline (54502.643 us; speedup 1.0000x reference)
//
#include <hip/hip_runtime.h>
#include <cstdint>

typedef uint32_t u32;
typedef _Float16 f16;
typedef f16 f16x2 __attribute__((ext_vector_type(2)));
typedef f16 f16x8 __attribute__((ext_vector_type(8)));
typedef float f32x4 __attribute__((ext_vector_type(4)));

static __device__ __forceinline__ u32 pack2(float a, float b) {
    f16x2 v;
    v.x = (f16)a;
    v.y = (f16)b;
    return __builtin_bit_cast(u32, v);
}

static __device__ __forceinline__ float dot2(u32 a, u32 b, float c) {
    return __builtin_amdgcn_fdot2(__builtin_bit_cast(f16x2, a),
                                  __builtin_bit_cast(f16x2, b), c, false);
}

static __device__ __forceinline__ unsigned short f16bits(float v) {
    return __builtin_bit_cast(unsigned short, (f16)v);
}

// barrier without vmcnt(0) drain (global enc stores must not stall the loop)
#define BAR() asm volatile("s_waitcnt lgkmcnt(0)\n\ts_barrier" ::: "memory")

#define MFMA(A, B, C) __builtin_amdgcn_mfma_f32_16x16x32_f16(A, B, C, 0, 0, 0)

// ---------------------------------------------------------------------------
// RNN kernel: 1 workgroup, 256 threads (4 waves), persistent over T steps.
// Hybrid pipe split (MFMA pipe was the R3 bottleneck: 16 MFMA/slot/SIMD
// ~310cy; matvec on MFMA is 16x redundant, dot2 on VALU is 2.4x denser):
//  - IH (critical): y_l = relu(Wih_l . cur + pre[l]) via 8 MFMAs/wave/slot,
//    accumulator SEEDED with pre[l] (f32x4 from LDS).
//  - HH (shadow, 1 slot slack): pre[l+1] = Whh_{l+1} . hid_{l+1} + b via
//    32 dot2/lane on the VALU, overlapping the MFMA pipe + LDS latency.
// Wave w owns rows 32w..32w+31 (2 M-tiles). IH A-frags resident (128 VGPR),
// HH weights resident as f16 pairs (128 VGPR). State f16 in LDS ping-pong;
// pre[4][128] f32 in LDS. 1 lgkm-only barrier/slot.
// ---------------------------------------------------------------------------
__global__ __launch_bounds__(256, 1) void rnn_kernel(
    const float* __restrict__ x0,
    const float* __restrict__ Wih, const float* __restrict__ Whh,
    const float* __restrict__ bih, const float* __restrict__ bhh,
    u32* __restrict__ enc, int T)
{
    __shared__ u32 buf[2][4][64];    // per-layer outputs, f16 pairs
    __shared__ float pre[4][128];    // Whh.hid + bias, f32

    const int tid  = threadIdx.x;
    const int w    = tid >> 6;     // wave 0..3
    const int lane = tid & 63;
    const int m    = lane & 15;    // A row-in-tile / D col
    const int g    = lane >> 4;    // k-group / D row-quad
    const int rsh  = w * 32 + (lane >> 1);   // shadow row (this lane)
    const int kh   = lane & 1;               // shadow k-half (64 elems)

    const f32x4 ZERO4 = {0.f, 0.f, 0.f, 0.f};

    // ---- resident IH A fragments (K=128: 4 ktiles)
    f16x8 ihA[4][2][4];            // [layer][tile][ktile]
    #pragma unroll
    for (int l = 0; l < 4; ++l)
        #pragma unroll
        for (int t = 0; t < 2; ++t) {
            const int row = w * 32 + t * 16 + m;
            #pragma unroll
            for (int kt = 0; kt < 4; ++kt) {
                const float* p = Wih + ((size_t)(l * 128 + row)) * 128
                                     + kt * 32 + g * 8;
                f16x8 v;
                #pragma unroll
                for (int e = 0; e < 8; ++e) v[e] = (f16)p[e];
                ihA[l][t][kt] = v;
            }
        }

    // ---- resident HH dot2 weights (row rsh, k-elems kh*64..kh*64+63)
    u32 whd[4][32];
    float bsh[4];
    #pragma unroll
    for (int l = 0; l < 4; ++l) {
        const float* p = Whh + ((size_t)(l * 128 + rsh)) * 128 + kh * 64;
        #pragma unroll
        for (int j = 0; j < 32; ++j)
            whd[l][j] = pack2(p[2 * j], p[2 * j + 1]);
        bsh[l] = bih[l * 128 + rsh] + bhh[l * 128 + rsh];
    }

    // ---- LDS init: buf[1] = { f16(x), 0, 0, 0 }   (step 0 reads parity 1)
    if (tid < 64)       buf[1][0][tid] = pack2(x0[2 * tid], x0[2 * tid + 1]);
    else if (tid < 256) ((u32*)buf[1])[tid] = 0u;
    __syncthreads();

    // shadow HH matvec: v = Whh_L . SRC + b_L (full row sum at both k-halves)
#define SHADOW(L, SRC, VOUT) do {                                             \
        const u32* _hb = &(SRC)[kh * 32];                                     \
        uint4 h0 = *(const uint4*)(_hb + 0);                                  \
        uint4 h1 = *(const uint4*)(_hb + 4);                                  \
        uint4 h2 = *(const uint4*)(_hb + 8);                                  \
        uint4 h3 = *(const uint4*)(_hb + 12);                                 \
        uint4 h4 = *(const uint4*)(_hb + 16);                                 \
        uint4 h5 = *(const uint4*)(_hb + 20);                                 \
        uint4 h6 = *(const uint4*)(_hb + 24);                                 \
        uint4 h7 = *(const uint4*)(_hb + 28);                                 \
        const u32* _wd = whd[L];                                              \
        float va = kh ? 0.f : bsh[L], vb = 0.f, vc = 0.f, vd = 0.f;           \
        va = dot2(h0.x, _wd[0], va);  vb = dot2(h0.y, _wd[1], vb);            \
        vc = dot2(h0.z, _wd[2], vc);  vd = dot2(h0.w, _wd[3], vd);            \
        va = dot2(h1.x, _wd[4], va);  vb = dot2(h1.y, _wd[5], vb);            \
        vc = dot2(h1.z, _wd[6], vc);  vd = dot2(h1.w, _wd[7], vd);            \
        va = dot2(h2.x, _wd[8], va);  vb = dot2(h2.y, _wd[9], vb);            \
        vc = dot2(h2.z, _wd[10], vc); vd = dot2(h2.w, _wd[11], vd);           \
        va = dot2(h3.x, _wd[12], va); vb = dot2(h3.y, _wd[13], vb);           \
        vc = dot2(h3.z, _wd[14], vc); vd = dot2(h3.w, _wd[15], vd);           \
        va = dot2(h4.x, _wd[16], va); vb = dot2(h4.y, _wd[17], vb);           \
        vc = dot2(h4.z, _wd[18], vc); vd = dot2(h4.w, _wd[19], vd);           \
        va = dot2(h5.x, _wd[20], va); vb = dot2(h5.y, _wd[21], vb);           \
        vc = dot2(h5.z, _wd[22], vc); vd = dot2(h5.w, _wd[23], vd);           \
        va = dot2(h6.x, _wd[24], va); vb = dot2(h6.y, _wd[25], vb);           \
        vc = dot2(h6.z, _wd[26], vc); vd = dot2(h6.w, _wd[27], vd);           \
        va = dot2(h7.x, _wd[28], va); vb = dot2(h7.y, _wd[29], vb);           \
        vc = dot2(h7.z, _wd[30], vc); vd = dot2(h7.w, _wd[31], vd);           \
        float _v = (va + vb) + (vc + vd);                                     \
        _v += __shfl_xor(_v, 1);                                              \
        VOUT = _v;                                                            \
    } while (0)

    // ---- init pre[0] for step 0: hid_0 = x (other layers' pre produced
    // in-loop one slot ahead of use)
    {
        float v;
        SHADOW(0, buf[1][0], v);
        if (kh == 0) pre[0][rsh] = v;
    }
    __syncthreads();

    // One layer-slot: critical IH (MFMA, seeded with pre) + shadow HH (dot2)
    // CURB = this slot's cur vector; SHSRC = hid_{l+1} source for next pre.
#define SLOT(l, CURB, SHSRC, STORE_ENC) do {                                  \
        const int lnx = (l + 1) & 3;                                          \
        const u32* _cb = (CURB);                                              \
        f32x4 pA = *(const f32x4*)&pre[l][w * 32 + g * 4];                    \
        f32x4 pB = *(const f32x4*)&pre[l][w * 32 + 16 + g * 4];               \
        f16x8 i0 = *(const f16x8*)(_cb + 0 * 16 + g * 4);                     \
        f16x8 i1 = *(const f16x8*)(_cb + 1 * 16 + g * 4);                     \
        f16x8 i2 = *(const f16x8*)(_cb + 2 * 16 + g * 4);                     \
        f16x8 i3 = *(const f16x8*)(_cb + 3 * 16 + g * 4);                     \
        f32x4 cA0 = MFMA(ihA[l][0][0], i0, pA);                               \
        f32x4 cB0 = MFMA(ihA[l][0][1], i1, ZERO4);                            \
        f32x4 cA1 = MFMA(ihA[l][1][0], i0, pB);                               \
        f32x4 cB1 = MFMA(ihA[l][1][1], i1, ZERO4);                            \
        cA0 = MFMA(ihA[l][0][2], i2, cA0);                                    \
        cB0 = MFMA(ihA[l][0][3], i3, cB0);                                    \
        cA1 = MFMA(ihA[l][1][2], i2, cA1);                                    \
        cB1 = MFMA(ihA[l][1][3], i3, cB1);                                    \
        float shv;                                                            \
        SHADOW(lnx, SHSRC, shv);    /* VALU work under the MFMAs */           \
        f32x4 d0 = cA0 + cB0;                                                 \
        f32x4 d1 = cA1 + cB1;                                                 \
        u32* _wb = &buf[_p][l][0];                                            \
        {                                                                     \
            u32 w0 = pack2(fmaxf(d0[0], 0.f), fmaxf(d0[1], 0.f));             \
            u32 w1 = pack2(fmaxf(d0[2], 0.f), fmaxf(d0[3], 0.f));             \
            u32 w2 = pack2(fmaxf(d1[0], 0.f), fmaxf(d1[1], 0.f));             \
            u32 w3 = pack2(fmaxf(d1[2], 0.f), fmaxf(d1[3], 0.f));             \
            if (m == 0) {                                                     \
                *(uint2*)(_wb + w * 16 + g * 2) = make_uint2(w0, w1);         \
                *(uint2*)(_wb + w * 16 + 8 + g * 2) = make_uint2(w2, w3);     \
                if (STORE_ENC) {                                              \
                    *(uint2*)(enc + (size_t)s * 64 + w * 16 + g * 2)          \
                        = make_uint2(w0, w1);                                 \
                    *(uint2*)(enc + (size_t)s * 64 + w * 16 + 8 + g * 2)      \
                        = make_uint2(w2, w3);                                 \
                }                                                             \
            }                                                                 \
        }                                                                     \
        if (kh == 0) pre[lnx][rsh] = shv;                                     \
        BAR();                                                                \
    } while (0)

    for (int s = 0; s < T; ++s) {
        const int _p = s & 1;
        const int _q = _p ^ 1;
        SLOT(0, &buf[_q][3][0], buf[_q][1], 0);
        SLOT(1, &buf[_p][0][0], buf[_q][2], 0);
        SLOT(2, &buf[_p][1][0], buf[_q][3], 0);
        SLOT(3, &buf[_p][2][0], buf[_p][0], 1);
    }
#undef SLOT
#undef SHADOW
}

// ---------------------------------------------------------------------------
// Heads kernel: grid (3 heads, T/32 row-segments), 256 threads. (unchanged)
// ---------------------------------------------------------------------------
__global__ __launch_bounds__(256) void heads_kernel(
    const u32* __restrict__ enc,
    const float* __restrict__ arw, const float* __restrict__ arb,
    const float* __restrict__ aw,  const float* __restrict__ ab,
    const float* __restrict__ prw, const float* __restrict__ prb,
    const float* __restrict__ pw,  const float* __restrict__ pb,
    const float* __restrict__ mrw, const float* __restrict__ mrb,
    const float* __restrict__ mw,  const float* __restrict__ mb,
    float* __restrict__ out, int T)
{
    const int head = blockIdx.x;
    const int r0 = blockIdx.y * 32;
    if (r0 >= T) return;

    const float *rbw, *rbb, *ow, *ob;
    int od, oc;
    if (head == 0)      { rbw = arw; rbb = arb; ow = aw; ob = ab; od = 8; oc = 0; }
    else if (head == 1) { rbw = prw; rbb = prb; ow = pw; ob = pb; od = 1; oc = 8; }
    else                { rbw = mrw; rbb = mrb; ow = mw; ob = mb; od = 1; oc = 9; }

    __shared__ u32 xs[32][64];
    __shared__ u32 hs[32][64];

    const int tid = threadIdx.x;

    #pragma unroll
    for (int rep = 0; rep < 8; ++rep) {
        int u = tid + rep * 256;
        int row = u >> 6, p = u & 63;
        xs[row][p] = enc[(size_t)(r0 + row) * 64 + p];
    }
    __syncthreads();

    const int j = tid & 127;
    const int rh = tid >> 7;

    float acc[16];
    u32 wreg[64];

#define PACKW(WPTR) do {                                                    \
        const float* _w = (WPTR);                                           \
        _Pragma("unroll")                                                   \
        for (int cc = 0; cc < 16; ++cc) {                                   \
            float4 aa = *(const float4*)(_w + cc * 8);                      \
            float4 bb = *(const float4*)(_w + cc * 8 + 4);                  \
            wreg[cc * 4 + 0] = pack2(aa.x, aa.y);                           \
            wreg[cc * 4 + 1] = pack2(aa.z, aa.w);                           \
            wreg[cc * 4 + 2] = pack2(bb.x, bb.y);                           \
            wreg[cc * 4 + 3] = pack2(bb.z, bb.w);                           \
        }                                                                   \
    } while (0)

#define MM16(SRC) do {                                                      \
        _Pragma("unroll")                                                   \
        for (int r = 0; r < 16; ++r) acc[r] = 0.f;                          \
        _Pragma("unroll")                                                   \
        for (int kp = 0; kp < 16; ++kp) {                                   \
            u32 w0 = wreg[kp * 4 + 0], w1 = wreg[kp * 4 + 1];               \
            u32 w2 = wreg[kp * 4 + 2], w3 = wreg[kp * 4 + 3];               \
            _Pragma("unroll")                                               \
            for (int r = 0; r < 16; ++r) {                                  \
                uint4 x4 = *(const uint4*)(&SRC[rh * 16 + r][kp * 4]);      \
                acc[r] = dot2(x4.x, w0, acc[r]);                            \
                acc[r] = dot2(x4.y, w1, acc[r]);                            \
                acc[r] = dot2(x4.z, w2, acc[r]);                            \
                acc[r] = dot2(x4.w, w3, acc[r]);                            \
            }                                                               \
        }                                                                   \
    } while (0)

    #pragma unroll
    for (int blk = 0; blk < 2; ++blk) {
        PACKW(rbw + (size_t)((blk * 2 + 0) * 128 + j) * 128);
        MM16(xs);
        {
            float b1 = rbb[(blk * 2 + 0) * 128 + j];
            #pragma unroll
            for (int r = 0; r < 16; ++r) {
                float v = acc[r] + b1;
                v = fmaxf(v, 0.2f * v);
                reinterpret_cast<unsigned short*>(&hs[rh * 16 + r][0])[j] = f16bits(v);
            }
        }
        __syncthreads();

        PACKW(rbw + (size_t)((blk * 2 + 1) * 128 + j) * 128);
        MM16(hs);
        {
            float b2 = rbb[(blk * 2 + 1) * 128 + j];
            #pragma unroll
            for (int r = 0; r < 16; ++r) {
                int row = rh * 16 + r;
                unsigned short xb =
                    reinterpret_cast<const unsigned short*>(&xs[row][0])[j];
                float xold = (float)__builtin_bit_cast(f16, xb);
                float v = xold + acc[r] + b2;
                v = fmaxf(v, 0.2f * v);
                reinterpret_cast<unsigned short*>(&xs[row][0])[j] = f16bits(v);
            }
        }
        __syncthreads();
    }

    {
        const int o = tid & 15;
        const int rr = tid >> 4;
        if (o < od) {
            PACKW(ow + (size_t)o * 128);
            float obv = ob[o];
            #pragma unroll
            for (int rs = 0; rs < 2; ++rs) {
                const int row = rr * 2 + rs;
                float a = 0.f;
                #pragma unroll
                for (int kp = 0; kp < 64; ++kp) a = dot2(xs[row][kp], wreg[kp], a);
                out[(size_t)(r0 + row) * 10 + oc + o] = a + obv;
            }
        }
    }
#undef PACKW
#undef MM16
}

extern "C" void kernel_launch(void* const* d_in, const int* in_sizes, int n_in,
                              void* d_out, int out_size, void* d_ws, size_t ws_size,
                              hipStream_t stream)
{
    const float* x   = (const float*)d_in[0];
    const float* Wih = (const float*)d_in[1];
    const float* Whh = (const float*)d_in[2];
    const float* bih = (const float*)d_in[3];
    const float* bhh = (const float*)d_in[4];
    const float* arw = (const float*)d_in[5];
    const float* arb = (const float*)d_in[6];
    const float* aw  = (const float*)d_in[7];
    const float* ab  = (const float*)d_in[8];
    const float* prw = (const float*)d_in[9];
    const float* prb = (const float*)d_in[10];
    const float* pw  = (const float*)d_in[11];
    const float* pb  = (const float*)d_in[12];
    const float* mrw = (const float*)d_in[13];
    const float* mrb = (const float*)d_in[14];
    const float* mw  = (const float*)d_in[15];
    const float* mb  = (const float*)d_in[16];

    const int T = out_size / 10;             // 32768
    u32* enc = (u32*)d_ws;                   // T*64 u32 (f16 pairs) = 8 MB

    rnn_kernel<<<1, 256, 0, stream>>>(x, Wih, Whh, bih, bhh, enc, T);

    heads_kernel<<<dim3(3, (T + 31) / 32), 256, 0, stream>>>(
        enc, arw, arb, aw, ab, prw, prb, pw, pb, mrw, mrb, mw, mb,
        (float*)d_out, T);
}

// Round 6
// 36202.737 us; speedup vs baseline: 1.5055x; 1.5055x over previous
//
#include <hip/hip_runtime.h>
#include <cstdint>

typedef uint32_t u32;
typedef _Float16 f16;
typedef f16 f16x2 __attribute__((ext_vector_type(2)));
typedef f16 f16x8 __attribute__((ext_vector_type(8)));
typedef float f32x4 __attribute__((ext_vector_type(4)));

static __device__ __forceinline__ u32 pack2(float a, float b) {
    f16x2 v;
    v.x = (f16)a;
    v.y = (f16)b;
    return __builtin_bit_cast(u32, v);
}

static __device__ __forceinline__ float dot2(u32 a, u32 b, float c) {
    return __builtin_amdgcn_fdot2(__builtin_bit_cast(f16x2, a),
                                  __builtin_bit_cast(f16x2, b), c, false);
}

static __device__ __forceinline__ unsigned short f16bits(float v) {
    return __builtin_bit_cast(unsigned short, (f16)v);
}

// barrier without vmcnt(0) drain (global enc stores must not stall the loop)
#define BAR() asm volatile("s_waitcnt lgkmcnt(0)\n\ts_barrier" ::: "memory")

#define MFMA(A, B, C) __builtin_amdgcn_mfma_f32_16x16x32_f16(A, B, C, 0, 0, 0)

// ---------------------------------------------------------------------------
// RNN kernel: 1 workgroup, 512 threads (8 waves = 2/SIMD), persistent.
// WAVE SPECIALIZATION (R5 failed because shadow VALU work serialized in-order
// inside the same wave as the MFMAs; m114 says separate MFMA-wave and
// VALU-wave on one CU overlap fully):
//  - waves 0-3 (IH, critical): y_l = relu(Wih_l . cur + pre[l]),
//    8 MFMAs + epilogue only. Wave w owns rows 32w..32w+31.
//  - waves 4-7 (HH, shadow, 1-slot slack): pre[l+1] = Whh_{l+1} . y + b
//    via 32 dot2/lane, writing f32 pre[4][128] in LDS.
// Per-wave weight residency halved vs R5 (IH: 128 VGPR of Wih frags;
// HH: 128 VGPR of Whh rows) -> ~190 VGPR each, 2 waves/SIMD.
// State f16 in LDS ping-pong buf[2][4][64]; 4 lgkm-only barriers/step.
// ---------------------------------------------------------------------------
__global__ __launch_bounds__(512, 2) void rnn_kernel(
    const float* __restrict__ x0,
    const float* __restrict__ Wih, const float* __restrict__ Whh,
    const float* __restrict__ bih, const float* __restrict__ bhh,
    u32* __restrict__ enc, int T)
{
    __shared__ u32 buf[2][4][64];    // per-layer outputs, f16 pairs
    __shared__ float pre[4][128];    // Whh.hid + bias, f32

    const int tid  = threadIdx.x;
    const int wave = tid >> 6;
    const int lane = tid & 63;
    const int w    = wave & 3;

    const f32x4 ZERO4 = {0.f, 0.f, 0.f, 0.f};

    // ---- LDS init: buf[1] = { f16(x), 0, 0, 0 }   (step 0 reads parity 1)
    if (tid < 64)       buf[1][0][tid] = pack2(x0[2 * tid], x0[2 * tid + 1]);
    else if (tid < 256) ((u32*)buf[1])[tid] = 0u;
    __syncthreads();

    if (wave < 4) {
        // ================= IH waves: critical MFMA chain =================
        const int m = lane & 15;    // A row-in-tile / D col
        const int g = lane >> 4;    // k-group / D row-quad

        f16x8 ihA[4][2][4];         // [layer][tile][ktile] resident Wih frags
        #pragma unroll
        for (int l = 0; l < 4; ++l)
            #pragma unroll
            for (int t = 0; t < 2; ++t) {
                const int row = w * 32 + t * 16 + m;
                #pragma unroll
                for (int kt = 0; kt < 4; ++kt) {
                    const float* p = Wih + ((size_t)(l * 128 + row)) * 128
                                         + kt * 32 + g * 8;
                    f16x8 v;
                    #pragma unroll
                    for (int e = 0; e < 8; ++e) v[e] = (f16)p[e];
                    ihA[l][t][kt] = v;
                }
            }
        BAR();   // matches HH waves' pre[0]-init barrier

#define SLOT_IH(l, P, CURB, S, STORE) do {                                    \
        const u32* _cb = (CURB);                                              \
        f32x4 pA = *(const f32x4*)&pre[l][w * 32 + g * 4];                    \
        f32x4 pB = *(const f32x4*)&pre[l][w * 32 + 16 + g * 4];               \
        f16x8 i0 = *(const f16x8*)(_cb + 0 * 16 + g * 4);                     \
        f16x8 i1 = *(const f16x8*)(_cb + 1 * 16 + g * 4);                     \
        f16x8 i2 = *(const f16x8*)(_cb + 2 * 16 + g * 4);                     \
        f16x8 i3 = *(const f16x8*)(_cb + 3 * 16 + g * 4);                     \
        f32x4 cA0 = MFMA(ihA[l][0][0], i0, pA);                               \
        f32x4 cB0 = MFMA(ihA[l][0][1], i1, ZERO4);                            \
        f32x4 cA1 = MFMA(ihA[l][1][0], i0, pB);                               \
        f32x4 cB1 = MFMA(ihA[l][1][1], i1, ZERO4);                            \
        cA0 = MFMA(ihA[l][0][2], i2, cA0);                                    \
        cB0 = MFMA(ihA[l][0][3], i3, cB0);                                    \
        cA1 = MFMA(ihA[l][1][2], i2, cA1);                                    \
        cB1 = MFMA(ihA[l][1][3], i3, cB1);                                    \
        f32x4 d0 = cA0 + cB0;                                                 \
        f32x4 d1 = cA1 + cB1;                                                 \
        u32 w0 = pack2(fmaxf(d0[0], 0.f), fmaxf(d0[1], 0.f));                 \
        u32 w1 = pack2(fmaxf(d0[2], 0.f), fmaxf(d0[3], 0.f));                 \
        u32 w2 = pack2(fmaxf(d1[0], 0.f), fmaxf(d1[1], 0.f));                 \
        u32 w3 = pack2(fmaxf(d1[2], 0.f), fmaxf(d1[3], 0.f));                 \
        if (m == 0) {                                                         \
            u32* _wb = &buf[P][l][0];                                         \
            *(uint2*)(_wb + w * 16 + g * 2) = make_uint2(w0, w1);             \
            *(uint2*)(_wb + w * 16 + 8 + g * 2) = make_uint2(w2, w3);         \
            if (STORE) {                                                      \
                *(uint2*)(enc + (size_t)(S) * 64 + w * 16 + g * 2)            \
                    = make_uint2(w0, w1);                                     \
                *(uint2*)(enc + (size_t)(S) * 64 + w * 16 + 8 + g * 2)        \
                    = make_uint2(w2, w3);                                     \
            }                                                                 \
        }                                                                     \
        BAR();                                                                \
    } while (0)

        for (int s = 0; s < T; s += 2) {
            // parity p=0, q=1
            SLOT_IH(0, 0, &buf[1][3][0], s, 0);
            SLOT_IH(1, 0, &buf[0][0][0], s, 0);
            SLOT_IH(2, 0, &buf[0][1][0], s, 0);
            SLOT_IH(3, 0, &buf[0][2][0], s, 1);
            // parity p=1, q=0
            SLOT_IH(0, 1, &buf[0][3][0], s + 1, 0);
            SLOT_IH(1, 1, &buf[1][0][0], s + 1, 0);
            SLOT_IH(2, 1, &buf[1][1][0], s + 1, 0);
            SLOT_IH(3, 1, &buf[1][2][0], s + 1, 1);
        }
#undef SLOT_IH
    } else {
        // ================= HH waves: shadow dot2 chain ===================
        const int rsh = w * 32 + (lane >> 1);   // owned row
        const int kh  = lane & 1;               // k-half (64 elems)

        u32 whd[4][32];
        float bsh[4];
        #pragma unroll
        for (int l = 0; l < 4; ++l) {
            const float* p = Whh + ((size_t)(l * 128 + rsh)) * 128 + kh * 64;
            #pragma unroll
            for (int j = 0; j < 32; ++j)
                whd[l][j] = pack2(p[2 * j], p[2 * j + 1]);
            bsh[l] = bih[l * 128 + rsh] + bhh[l * 128 + rsh];
        }

#define SHADOW(L, SRC, VOUT) do {                                             \
        const u32* _hb = &(SRC)[kh * 32];                                     \
        uint4 h0 = *(const uint4*)(_hb + 0);                                  \
        uint4 h1 = *(const uint4*)(_hb + 4);                                  \
        uint4 h2 = *(const uint4*)(_hb + 8);                                  \
        uint4 h3 = *(const uint4*)(_hb + 12);                                 \
        uint4 h4 = *(const uint4*)(_hb + 16);                                 \
        uint4 h5 = *(const uint4*)(_hb + 20);                                 \
        uint4 h6 = *(const uint4*)(_hb + 24);                                 \
        uint4 h7 = *(const uint4*)(_hb + 28);                                 \
        const u32* _wd = whd[L];                                              \
        float va = kh ? 0.f : bsh[L], vb = 0.f, vc = 0.f, vd = 0.f;           \
        va = dot2(h0.x, _wd[0], va);  vb = dot2(h0.y, _wd[1], vb);            \
        vc = dot2(h0.z, _wd[2], vc);  vd = dot2(h0.w, _wd[3], vd);            \
        va = dot2(h1.x, _wd[4], va);  vb = dot2(h1.y, _wd[5], vb);            \
        vc = dot2(h1.z, _wd[6], vc);  vd = dot2(h1.w, _wd[7], vd);            \
        va = dot2(h2.x, _wd[8], va);  vb = dot2(h2.y, _wd[9], vb);            \
        vc = dot2(h2.z, _wd[10], vc); vd = dot2(h2.w, _wd[11], vd);           \
        va = dot2(h3.x, _wd[12], va); vb = dot2(h3.y, _wd[13], vb);           \
        vc = dot2(h3.z, _wd[14], vc); vd = dot2(h3.w, _wd[15], vd);           \
        va = dot2(h4.x, _wd[16], va); vb = dot2(h4.y, _wd[17], vb);           \
        vc = dot2(h4.z, _wd[18], vc); vd = dot2(h4.w, _wd[19], vd);           \
        va = dot2(h5.x, _wd[20], va); vb = dot2(h5.y, _wd[21], vb);           \
        vc = dot2(h5.z, _wd[22], vc); vd = dot2(h5.w, _wd[23], vd);           \
        va = dot2(h6.x, _wd[24], va); vb = dot2(h6.y, _wd[25], vb);           \
        vc = dot2(h6.z, _wd[26], vc); vd = dot2(h6.w, _wd[27], vd);           \
        va = dot2(h7.x, _wd[28], va); vb = dot2(h7.y, _wd[29], vb);           \
        vc = dot2(h7.z, _wd[30], vc); vd = dot2(h7.w, _wd[31], vd);           \
        float _v = (va + vb) + (vc + vd);                                     \
        _v += __shfl_xor(_v, 1);                                              \
        VOUT = _v;                                                            \
    } while (0)

        // init pre[0] for step 0 (hid_0 = x); pre[1..3] produced in-loop
        {
            float v;
            SHADOW(0, buf[1][0], v);
            if (kh == 0) pre[0][rsh] = v;
        }
        BAR();   // matches IH waves' post-weight-load barrier

#define SLOT_HH(LNX, SRC) do {                                                \
        float shv;                                                            \
        SHADOW(LNX, SRC, shv);                                                \
        if (kh == 0) pre[LNX][rsh] = shv;                                     \
        BAR();                                                                \
    } while (0)

        for (int s = 0; s < T; s += 2) {
            // parity p=0, q=1
            SLOT_HH(1, buf[1][1]);
            SLOT_HH(2, buf[1][2]);
            SLOT_HH(3, buf[1][3]);
            SLOT_HH(0, buf[0][0]);
            // parity p=1, q=0
            SLOT_HH(1, buf[0][1]);
            SLOT_HH(2, buf[0][2]);
            SLOT_HH(3, buf[0][3]);
            SLOT_HH(0, buf[1][0]);
        }
#undef SLOT_HH
#undef SHADOW
    }
}

// ---------------------------------------------------------------------------
// Heads kernel: grid (3 heads, T/32 row-segments), 256 threads. (unchanged)
// ---------------------------------------------------------------------------
__global__ __launch_bounds__(256) void heads_kernel(
    const u32* __restrict__ enc,
    const float* __restrict__ arw, const float* __restrict__ arb,
    const float* __restrict__ aw,  const float* __restrict__ ab,
    const float* __restrict__ prw, const float* __restrict__ prb,
    const float* __restrict__ pw,  const float* __restrict__ pb,
    const float* __restrict__ mrw, const float* __restrict__ mrb,
    const float* __restrict__ mw,  const float* __restrict__ mb,
    float* __restrict__ out, int T)
{
    const int head = blockIdx.x;
    const int r0 = blockIdx.y * 32;
    if (r0 >= T) return;

    const float *rbw, *rbb, *ow, *ob;
    int od, oc;
    if (head == 0)      { rbw = arw; rbb = arb; ow = aw; ob = ab; od = 8; oc = 0; }
    else if (head == 1) { rbw = prw; rbb = prb; ow = pw; ob = pb; od = 1; oc = 8; }
    else                { rbw = mrw; rbb = mrb; ow = mw; ob = mb; od = 1; oc = 9; }

    __shared__ u32 xs[32][64];
    __shared__ u32 hs[32][64];

    const int tid = threadIdx.x;

    #pragma unroll
    for (int rep = 0; rep < 8; ++rep) {
        int u = tid + rep * 256;
        int row = u >> 6, p = u & 63;
        xs[row][p] = enc[(size_t)(r0 + row) * 64 + p];
    }
    __syncthreads();

    const int j = tid & 127;
    const int rh = tid >> 7;

    float acc[16];
    u32 wreg[64];

#define PACKW(WPTR) do {                                                    \
        const float* _w = (WPTR);                                           \
        _Pragma("unroll")                                                   \
        for (int cc = 0; cc < 16; ++cc) {                                   \
            float4 aa = *(const float4*)(_w + cc * 8);                      \
            float4 bb = *(const float4*)(_w + cc * 8 + 4);                  \
            wreg[cc * 4 + 0] = pack2(aa.x, aa.y);                           \
            wreg[cc * 4 + 1] = pack2(aa.z, aa.w);                           \
            wreg[cc * 4 + 2] = pack2(bb.x, bb.y);                           \
            wreg[cc * 4 + 3] = pack2(bb.z, bb.w);                           \
        }                                                                   \
    } while (0)

#define MM16(SRC) do {                                                      \
        _Pragma("unroll")                                                   \
        for (int r = 0; r < 16; ++r) acc[r] = 0.f;                          \
        _Pragma("unroll")                                                   \
        for (int kp = 0; kp < 16; ++kp) {                                   \
            u32 w0 = wreg[kp * 4 + 0], w1 = wreg[kp * 4 + 1];               \
            u32 w2 = wreg[kp * 4 + 2], w3 = wreg[kp * 4 + 3];               \
            _Pragma("unroll")                                               \
            for (int r = 0; r < 16; ++r) {                                  \
                uint4 x4 = *(const uint4*)(&SRC[rh * 16 + r][kp * 4]);      \
                acc[r] = dot2(x4.x, w0, acc[r]);                            \
                acc[r] = dot2(x4.y, w1, acc[r]);                            \
                acc[r] = dot2(x4.z, w2, acc[r]);                            \
                acc[r] = dot2(x4.w, w3, acc[r]);                            \
            }                                                               \
        }                                                                   \
    } while (0)

    #pragma unroll
    for (int blk = 0; blk < 2; ++blk) {
        PACKW(rbw + (size_t)((blk * 2 + 0) * 128 + j) * 128);
        MM16(xs);
        {
            float b1 = rbb[(blk * 2 + 0) * 128 + j];
            #pragma unroll
            for (int r = 0; r < 16; ++r) {
                float v = acc[r] + b1;
                v = fmaxf(v, 0.2f * v);
                reinterpret_cast<unsigned short*>(&hs[rh * 16 + r][0])[j] = f16bits(v);
            }
        }
        __syncthreads();

        PACKW(rbw + (size_t)((blk * 2 + 1) * 128 + j) * 128);
        MM16(hs);
        {
            float b2 = rbb[(blk * 2 + 1) * 128 + j];
            #pragma unroll
            for (int r = 0; r < 16; ++r) {
                int row = rh * 16 + r;
                unsigned short xb =
                    reinterpret_cast<const unsigned short*>(&xs[row][0])[j];
                float xold = (float)__builtin_bit_cast(f16, xb);
                float v = xold + acc[r] + b2;
                v = fmaxf(v, 0.2f * v);
                reinterpret_cast<unsigned short*>(&xs[row][0])[j] = f16bits(v);
            }
        }
        __syncthreads();
    }

    {
        const int o = tid & 15;
        const int rr = tid >> 4;
        if (o < od) {
            PACKW(ow + (size_t)o * 128);
            float obv = ob[o];
            #pragma unroll
            for (int rs = 0; rs < 2; ++rs) {
                const int row = rr * 2 + rs;
                float a = 0.f;
                #pragma unroll
                for (int kp = 0; kp < 64; ++kp) a = dot2(xs[row][kp], wreg[kp], a);
                out[(size_t)(r0 + row) * 10 + oc + o] = a + obv;
            }
        }
    }
#undef PACKW
#undef MM16
}

extern "C" void kernel_launch(void* const* d_in, const int* in_sizes, int n_in,
                              void* d_out, int out_size, void* d_ws, size_t ws_size,
                              hipStream_t stream)
{
    const float* x   = (const float*)d_in[0];
    const float* Wih = (const float*)d_in[1];
    const float* Whh = (const float*)d_in[2];
    const float* bih = (const float*)d_in[3];
    const float* bhh = (const float*)d_in[4];
    const float* arw = (const float*)d_in[5];
    const float* arb = (const float*)d_in[6];
    const float* aw  = (const float*)d_in[7];
    const float* ab  = (const float*)d_in[8];
    const float* prw = (const float*)d_in[9];
    const float* prb = (const float*)d_in[10];
    const float* pw  = (const float*)d_in[11];
    const float* pb  = (const float*)d_in[12];
    const float* mrw = (const float*)d_in[13];
    const float* mrb = (const float*)d_in[14];
    const float* mw  = (const float*)d_in[15];
    const float* mb  = (const float*)d_in[16];

    const int T = out_size / 10;             // 32768
    u32* enc = (u32*)d_ws;                   // T*64 u32 (f16 pairs) = 8 MB

    rnn_kernel<<<1, 512, 0, stream>>>(x, Wih, Whh, bih, bhh, enc, T);

    heads_kernel<<<dim3(3, (T + 31) / 32), 256, 0, stream>>>(
        enc, arw, arb, aw, ab, prw, prb, pw, pb, mrw, mrb, mw, mb,
        (float*)d_out, T);
}